// Round 3
// baseline (28465.176 us; speedup 1.0000x reference)
//
#include <hip/hip_runtime.h>
#include <hip/hip_bf16.h>

// GRU forward, B=64 S=512 I=512 H=1024. fp32 I/O, bf16 MFMA internals.
// Round 3: single persistent kernel, 128 co-resident WGs, flag-array global
// barriers (2 per step) instead of 1024 kernel launches.
// Phase 1: z & r (fused x@W^T + h@U^T, K=1536), 128 jobs = 2 gates x 64 cols.
// Phase 2: h_hat + h update, 64 jobs. 4-way K-split per WG, LDS reduce.

#define B_ 64
#define S_ 512
#define I_ 512
#define H_ 1024
#define NWG 128
#define FSTRIDE 32  // ints between flags (128 B)

typedef short short8 __attribute__((ext_vector_type(8)));
typedef float floatx4 __attribute__((ext_vector_type(4)));

__device__ inline floatx4 mfma16(short8 a, short8 b, floatx4 c) {
    return __builtin_amdgcn_mfma_f32_16x16x32_bf16(a, b, c, 0, 0, 0);
}

__device__ inline short f2bf(float f) {
    union { float f; unsigned u; } v; v.f = f;
    unsigned r = (v.u + 0x7FFFu + ((v.u >> 16) & 1u)) >> 16;
    return (short)r;
}

__device__ inline short8 ld8(const short* p) {
    return *reinterpret_cast<const short8*>(p);
}

__device__ inline short8 loadA_f32(const float* p) {
    const float4* q = reinterpret_cast<const float4*>(p);
    float4 f0 = q[0], f1 = q[1];
    short8 a;
    a[0] = f2bf(f0.x); a[1] = f2bf(f0.y); a[2] = f2bf(f0.z); a[3] = f2bf(f0.w);
    a[4] = f2bf(f1.x); a[5] = f2bf(f1.y); a[6] = f2bf(f1.z); a[7] = f2bf(f1.w);
    return a;
}

// ---- bulk fp32 -> bf16 ----
__global__ __launch_bounds__(256) void cvt8k(const float* __restrict__ src,
                                             short* __restrict__ dst, int n8) {
    int i = blockIdx.x * 256 + threadIdx.x;
    if (i >= n8) return;
    const float4* p = reinterpret_cast<const float4*>(src) + (size_t)i * 2;
    float4 f0 = p[0], f1 = p[1];
    short8 o;
    o[0] = f2bf(f0.x); o[1] = f2bf(f0.y); o[2] = f2bf(f0.z); o[3] = f2bf(f0.w);
    o[4] = f2bf(f1.x); o[5] = f2bf(f1.y); o[6] = f2bf(f1.z); o[7] = f2bf(f1.w);
    reinterpret_cast<short8*>(dst)[i] = o;
}

// ---- init h state + zero flags ----
__global__ __launch_bounds__(256) void gru_init(const float* __restrict__ h0,
                                                float* __restrict__ h_f32,
                                                short* __restrict__ h_bf16,
                                                int* __restrict__ flags) {
    int i = blockIdx.x * 256 + threadIdx.x;
    if (i < B_ * H_) {
        float v = h0[i];
        h_f32[i] = v;
        h_bf16[i] = f2bf(v);
    }
    if (i < NWG * FSTRIDE) flags[i] = 0;
}

__device__ inline void gbar(int* flags, int ep) {
    int tid = threadIdx.x;
    __syncthreads();
    if (tid == 0)
        __hip_atomic_store(&flags[blockIdx.x * FSTRIDE], ep,
                           __ATOMIC_RELEASE, __HIP_MEMORY_SCOPE_AGENT);
    if (tid < NWG) {
        while (__hip_atomic_load(&flags[tid * FSTRIDE],
                                 __ATOMIC_RELAXED, __HIP_MEMORY_SCOPE_AGENT) < ep)
            __builtin_amdgcn_s_sleep(1);
    }
    __syncthreads();
    __threadfence();
}

// K mapping: k in [0,512) -> x/W part; k in [512,1536) -> (h or rh)/U part.
// MFMA 16x16x32 bf16 NT (m89/m91-verified): D col=lane&15, row=quad*4+reg.
template <int MODE>  // 0: x fp32 on-the-fly cvt, 1: xb bf16 precomputed
__global__ __launch_bounds__(256) void gru_persist(
    const float* __restrict__ x, const short* __restrict__ xb,
    const short* __restrict__ Wzb, const short* __restrict__ Wrb, const short* __restrict__ Whb,
    const short* __restrict__ Uzb, const short* __restrict__ Urb, const short* __restrict__ Uhb,
    const float* __restrict__ bz, const float* __restrict__ br, const float* __restrict__ bh,
    float* __restrict__ h_f32, short* __restrict__ h_b,
    float* __restrict__ z_f32, short* __restrict__ rh,
    int* __restrict__ flags, float* __restrict__ out)
{
    __shared__ floatx4 red[3 * 4 * 64];  // [wave-1][bg][lane]

    int wg = blockIdx.x;
    int tid = threadIdx.x;
    int wave = tid >> 6, lane = tid & 63;
    int m16 = lane & 15, quad = lane >> 4;

    int g1 = wg >> 6, c1 = wg & 63;       // phase-1 job
    const short* W1 = g1 ? Wrb : Wzb;
    const short* U1 = g1 ? Urb : Uzb;
    const float* bias1 = g1 ? br : bz;
    int j1 = c1 * 16 + m16;
    int j2 = wg * 16 + m16;               // phase-2 job (wg<64)

    for (int t = 0; t < S_; ++t) {
        // ======== phase 1: z and r ========
        {
            floatx4 acc[4];
#pragma unroll
            for (int bg = 0; bg < 4; ++bg) acc[bg] = floatx4{0.f, 0.f, 0.f, 0.f};
#pragma unroll 4
            for (int s = 0; s < 12; ++s) {
                int k = wave * 384 + s * 32;
                short8 bfrag = (k < 512)
                    ? ld8(W1 + (size_t)j1 * I_ + k + quad * 8)
                    : ld8(U1 + (size_t)j1 * H_ + (k - 512) + quad * 8);
#pragma unroll
                for (int bg = 0; bg < 4; ++bg) {
                    int b = bg * 16 + m16;
                    short8 afrag;
                    if (k < 512) {
                        if (MODE) afrag = ld8(xb + ((size_t)b * S_ + t) * I_ + k + quad * 8);
                        else      afrag = loadA_f32(x + ((size_t)b * S_ + t) * I_ + k + quad * 8);
                    } else {
                        afrag = ld8(h_b + (size_t)b * H_ + (k - 512) + quad * 8);
                    }
                    acc[bg] = mfma16(afrag, bfrag, acc[bg]);
                }
            }
            if (wave > 0) {
#pragma unroll
                for (int bg = 0; bg < 4; ++bg)
                    red[((wave - 1) * 4 + bg) * 64 + lane] = acc[bg];
            }
            __syncthreads();
            if (wave == 0) {
                float bv = bias1[j1];
#pragma unroll
                for (int bg = 0; bg < 4; ++bg) {
                    floatx4 a = acc[bg];
#pragma unroll
                    for (int w = 0; w < 3; ++w) a += red[(w * 4 + bg) * 64 + lane];
#pragma unroll
                    for (int r = 0; r < 4; ++r) {
                        int b = bg * 16 + quad * 4 + r;
                        float sg = 1.0f / (1.0f + __expf(-(a[r] + bv)));
                        size_t idx = (size_t)b * H_ + j1;
                        if (g1 == 0) z_f32[idx] = sg;
                        else         rh[idx] = f2bf(sg * h_f32[idx]);
                    }
                }
            }
        }
        gbar(flags, 2 * t + 1);

        // ======== phase 2: h_hat + h update ========
        if (wg < 64) {
            floatx4 acc[4];
#pragma unroll
            for (int bg = 0; bg < 4; ++bg) acc[bg] = floatx4{0.f, 0.f, 0.f, 0.f};
#pragma unroll 4
            for (int s = 0; s < 12; ++s) {
                int k = wave * 384 + s * 32;
                short8 bfrag = (k < 512)
                    ? ld8(Whb + (size_t)j2 * I_ + k + quad * 8)
                    : ld8(Uhb + (size_t)j2 * H_ + (k - 512) + quad * 8);
#pragma unroll
                for (int bg = 0; bg < 4; ++bg) {
                    int b = bg * 16 + m16;
                    short8 afrag;
                    if (k < 512) {
                        if (MODE) afrag = ld8(xb + ((size_t)b * S_ + t) * I_ + k + quad * 8);
                        else      afrag = loadA_f32(x + ((size_t)b * S_ + t) * I_ + k + quad * 8);
                    } else {
                        afrag = ld8(rh + (size_t)b * H_ + (k - 512) + quad * 8);
                    }
                    acc[bg] = mfma16(afrag, bfrag, acc[bg]);
                }
            }
            if (wave > 0) {
#pragma unroll
                for (int bg = 0; bg < 4; ++bg)
                    red[((wave - 1) * 4 + bg) * 64 + lane] = acc[bg];
            }
            __syncthreads();
            if (wave == 0) {
                float bv = bh[j2];
#pragma unroll
                for (int bg = 0; bg < 4; ++bg) {
                    floatx4 a = acc[bg];
#pragma unroll
                    for (int w = 0; w < 3; ++w) a += red[(w * 4 + bg) * 64 + lane];
#pragma unroll
                    for (int r = 0; r < 4; ++r) {
                        int b = bg * 16 + quad * 4 + r;
                        float hh = tanhf(a[r] + bv);
                        size_t idx = (size_t)b * H_ + j2;
                        float z = z_f32[idx];
                        float hv = h_f32[idx];
                        float hn = fmaf(z, hh - hv, hv);
                        h_f32[idx] = hn;
                        h_b[idx] = f2bf(hn);
                        out[(size_t)b * S_ * H_ + (size_t)t * H_ + j2] = hn;
                        if (t == S_ - 1) out[(size_t)B_ * S_ * H_ + idx] = hn;
                    }
                }
            }
        }
        gbar(flags, 2 * t + 2);
    }
}

extern "C" void kernel_launch(void* const* d_in, const int* in_sizes, int n_in,
                              void* d_out, int out_size, void* d_ws, size_t ws_size,
                              hipStream_t stream) {
    const float* x  = (const float*)d_in[0];
    const float* h0 = (const float*)d_in[1];
    const float* Wz = (const float*)d_in[2];
    const float* bz = (const float*)d_in[3];
    const float* Uz = (const float*)d_in[4];
    const float* Wr = (const float*)d_in[5];
    const float* br = (const float*)d_in[6];
    const float* Ur = (const float*)d_in[7];
    const float* Wh = (const float*)d_in[8];
    const float* bh = (const float*)d_in[9];
    const float* Uh = (const float*)d_in[10];
    float* out = (float*)d_out;

    const int HB = B_ * H_;
    const int WI = H_ * I_;
    const int UU = H_ * H_;
    const size_t XN = (size_t)B_ * S_ * I_;

    char* w = (char*)d_ws;
    float* h_f32 = (float*)w;  w += (size_t)HB * 4;
    float* z_f32 = (float*)w;  w += (size_t)HB * 4;
    short* h_b   = (short*)w;  w += (size_t)HB * 2;
    short* rh    = (short*)w;  w += (size_t)HB * 2;
    int*   flags = (int*)w;    w += (size_t)NWG * FSTRIDE * 4;
    short* Wzb   = (short*)w;  w += (size_t)WI * 2;
    short* Wrb   = (short*)w;  w += (size_t)WI * 2;
    short* Whb   = (short*)w;  w += (size_t)WI * 2;
    short* Uzb   = (short*)w;  w += (size_t)UU * 2;
    short* Urb   = (short*)w;  w += (size_t)UU * 2;
    short* Uhb   = (short*)w;  w += (size_t)UU * 2;
    size_t base_need = (size_t)(w - (char*)d_ws);
    bool XB = ws_size >= base_need + XN * 2;
    short* xb = (short*)w;

    gru_init<<<dim3(HB / 256), 256, 0, stream>>>(h0, h_f32, h_b, flags);
    cvt8k<<<dim3(WI / 8 / 256), 256, 0, stream>>>(Wz, Wzb, WI / 8);
    cvt8k<<<dim3(WI / 8 / 256), 256, 0, stream>>>(Wr, Wrb, WI / 8);
    cvt8k<<<dim3(WI / 8 / 256), 256, 0, stream>>>(Wh, Whb, WI / 8);
    cvt8k<<<dim3(UU / 8 / 256), 256, 0, stream>>>(Uz, Uzb, UU / 8);
    cvt8k<<<dim3(UU / 8 / 256), 256, 0, stream>>>(Ur, Urb, UU / 8);
    cvt8k<<<dim3(UU / 8 / 256), 256, 0, stream>>>(Uh, Uhb, UU / 8);
    if (XB) {
        cvt8k<<<dim3((int)(XN / 8 / 256)), 256, 0, stream>>>(x, xb, (int)(XN / 8));
        gru_persist<1><<<dim3(NWG), 256, 0, stream>>>(
            x, xb, Wzb, Wrb, Whb, Uzb, Urb, Uhb, bz, br, bh,
            h_f32, h_b, z_f32, rh, flags, out);
    } else {
        gru_persist<0><<<dim3(NWG), 256, 0, stream>>>(
            x, xb, Wzb, Wrb, Whb, Uzb, Urb, Uhb, bz, br, bh,
            h_f32, h_b, z_f32, rh, flags, out);
    }
}